// Round 1
// baseline (605.245 us; speedup 1.0000x reference)
//
#include <hip/hip_runtime.h>

#ifndef FILLV
#define FILLV (-9999.0f)
#endif
#define SLOT_CAP 40

// ---------------------------------------------------------------------------
// Kernel 1: per-candidate MLP (3->18->36->36->1 with ReLU) + bucket scatter.
// Each thread handles one candidate k. Weights are uniform -> compiler emits
// scalar (s_load) reads through the constant cache; activations live in VGPRs.
// Packs (idx1:10 bits | float bits:32 | k:20 bits) into 64 bits per slot so
// the reducer can resolve duplicate (row,col) slots by "largest k wins"
// (JAX scatter .set applies updates in order; last update wins).
// ---------------------------------------------------------------------------
__global__ __launch_bounds__(256) void mlp_scatter(
    const float* __restrict__ in,    // [3, K]
    const int*   __restrict__ tind,  // [2, K]
    const float* __restrict__ W1, const float* __restrict__ b1,
    const float* __restrict__ W2, const float* __restrict__ b2,
    const float* __restrict__ W3, const float* __restrict__ b3,
    const float* __restrict__ W4, const float* __restrict__ b4,
    int* __restrict__ rowcnt,
    unsigned long long* __restrict__ rowslot,
    int K, int cap)
{
    int k = blockIdx.x * 256 + threadIdx.x;
    if (k >= K) return;

    float x0 = in[k];
    float x1 = in[K + k];
    float x2 = in[2 * K + k];

    float h1[18];
#pragma unroll
    for (int j = 0; j < 18; ++j) {
        float a = b1[j];
        a = fmaf(W1[j * 3 + 0], x0, a);
        a = fmaf(W1[j * 3 + 1], x1, a);
        a = fmaf(W1[j * 3 + 2], x2, a);
        h1[j] = fmaxf(a, 0.0f);
    }
    float h2[36];
#pragma unroll
    for (int j = 0; j < 36; ++j) {
        float a = b2[j];
#pragma unroll
        for (int i = 0; i < 18; ++i) a = fmaf(W2[j * 18 + i], h1[i], a);
        h2[j] = fmaxf(a, 0.0f);
    }
    float h3[36];
#pragma unroll
    for (int j = 0; j < 36; ++j) {
        float a = b3[j];
#pragma unroll
        for (int i = 0; i < 36; ++i) a = fmaf(W3[j * 36 + i], h2[i], a);
        h3[j] = fmaxf(a, 0.0f);
    }
    float x = b4[0];
#pragma unroll
    for (int i = 0; i < 36; ++i) x = fmaf(W4[i], h3[i], x);

    int row = tind[k];
    int col = tind[K + k];
    int r = atomicAdd(&rowcnt[row], 1);
    if (r < cap) {
        unsigned long long pack =
            ((unsigned long long)(unsigned)col << 52) |
            ((unsigned long long)__float_as_uint(x) << 20) |
            (unsigned long long)(unsigned)k;
        rowslot[(size_t)row * cap + r] = pack;
    }
}

// ---------------------------------------------------------------------------
// Kernel 2: per-row winner resolution + max reduce.
// One thread per row. Candidate a survives iff no candidate b exists with the
// same idx1 and a larger k (strictly) -- i.e. last scatter update wins per
// slot. Output = max over survivors, FILL if row empty. Order-independent,
// so nondeterministic atomicAdd slot ordering does not affect the result.
// ---------------------------------------------------------------------------
__global__ __launch_bounds__(256) void row_reduce(
    const int* __restrict__ rowcnt,
    const unsigned long long* __restrict__ rowslot,
    float* __restrict__ out,
    int n3d, int cap)
{
    int i = blockIdx.x * 256 + threadIdx.x;
    if (i >= n3d) return;
    int c = rowcnt[i];
    if (c > cap) c = cap;
    const unsigned long long* s = rowslot + (size_t)i * cap;
    float best = FILLV;
    for (int a = 0; a < c; ++a) {
        unsigned long long pa = s[a];
        unsigned ja = (unsigned)(pa >> 52);
        unsigned ka = (unsigned)pa & 0xFFFFFu;
        bool win = true;
        for (int b = 0; b < c; ++b) {
            unsigned long long pb = s[b];
            if ((unsigned)(pb >> 52) == ja && ((unsigned)pb & 0xFFFFFu) > ka) {
                win = false;
            }
        }
        if (win) best = fmaxf(best, __uint_as_float((unsigned)(pa >> 20)));
    }
    out[i] = best;
}

extern "C" void kernel_launch(void* const* d_in, const int* in_sizes, int n_in,
                              void* d_out, int out_size, void* d_ws, size_t ws_size,
                              hipStream_t stream) {
    const float* input_1 = (const float*)d_in[0];
    // d_in[1] = T_out (unused: never materialized)
    const int*   tind    = (const int*)d_in[2];
    const float* W1 = (const float*)d_in[3];
    const float* b1 = (const float*)d_in[4];
    const float* W2 = (const float*)d_in[5];
    const float* b2 = (const float*)d_in[6];
    const float* W3 = (const float*)d_in[7];
    const float* b3 = (const float*)d_in[8];
    const float* W4 = (const float*)d_in[9];
    const float* b4 = (const float*)d_in[10];
    float* out = (float*)d_out;

    const int K   = in_sizes[0] / 3;   // 800000
    const int n3d = out_size;          // 100000

    // Workspace layout: rowcnt [n3d] ints, then rowslot [n3d * cap] u64.
    size_t cnt_bytes = (size_t)n3d * sizeof(int);
    cnt_bytes = (cnt_bytes + 15) & ~(size_t)15;
    int cap = SLOT_CAP;
    size_t avail = (ws_size > cnt_bytes) ? (ws_size - cnt_bytes) : 0;
    int max_cap = (int)(avail / ((size_t)n3d * sizeof(unsigned long long)));
    if (max_cap < cap) cap = max_cap;  // degrade gracefully if ws is tiny

    int* rowcnt = (int*)d_ws;
    unsigned long long* rowslot =
        (unsigned long long*)((char*)d_ws + cnt_bytes);

    hipMemsetAsync(rowcnt, 0, (size_t)n3d * sizeof(int), stream);

    int blocks_k = (K + 255) / 256;
    mlp_scatter<<<blocks_k, 256, 0, stream>>>(
        input_1, tind, W1, b1, W2, b2, W3, b3, W4, b4,
        rowcnt, rowslot, K, cap);

    int blocks_r = (n3d + 255) / 256;
    row_reduce<<<blocks_r, 256, 0, stream>>>(rowcnt, rowslot, out, n3d, cap);
}

// Round 2
// 597.593 us; speedup vs baseline: 1.0128x; 1.0128x over previous
//
#include <hip/hip_runtime.h>

#ifndef FILLV
#define FILLV (-9999.0f)
#endif
#define SLOT_CAP 40

typedef unsigned long long u64;

// ---------------------------------------------------------------------------
// Kernel 1: per-candidate MLP (3->18->36->36->1 with ReLU) + bucket scatter.
// One thread per candidate k. Weight addresses are wave-uniform with
// compile-time offsets after full unroll -> scalar cache (s_load), so the
// VALU only issues the ~2034 FMAs (floor ~21 us at 157 TF fp32).
// Packs (idx1:10 | f32 bits:32 | k:20) into 8 bytes per bucket slot so the
// reducer can resolve duplicate (row,col) scatters by "largest k wins"
// (JAX .set applies updates in order; last update wins). Bucket array is
// SLOT-MAJOR [cap][n3d] so the reducer reads coalesced.
// ---------------------------------------------------------------------------
__global__ __launch_bounds__(256) void mlp_scatter(
    const float* __restrict__ in,    // [3, K]
    const int*   __restrict__ tind,  // [2, K]
    const float* __restrict__ W1, const float* __restrict__ b1,
    const float* __restrict__ W2, const float* __restrict__ b2,
    const float* __restrict__ W3, const float* __restrict__ b3,
    const float* __restrict__ W4, const float* __restrict__ b4,
    int* __restrict__ rowcnt,
    u64* __restrict__ rowslot,
    int K, int n3d, int cap)
{
    int k = blockIdx.x * 256 + threadIdx.x;
    if (k >= K) return;

    float x0 = in[k];
    float x1 = in[K + k];
    float x2 = in[2 * K + k];

    float h1[18];
#pragma unroll
    for (int j = 0; j < 18; ++j) {
        float a = b1[j];
        a = fmaf(W1[j * 3 + 0], x0, a);
        a = fmaf(W1[j * 3 + 1], x1, a);
        a = fmaf(W1[j * 3 + 2], x2, a);
        h1[j] = fmaxf(a, 0.0f);
    }
    float h2[36];
#pragma unroll
    for (int j = 0; j < 36; ++j) {
        float a = b2[j];
#pragma unroll
        for (int i = 0; i < 18; ++i) a = fmaf(W2[j * 18 + i], h1[i], a);
        h2[j] = fmaxf(a, 0.0f);
    }
    float h3[36];
#pragma unroll
    for (int j = 0; j < 36; ++j) {
        float a = b3[j];
#pragma unroll
        for (int i = 0; i < 36; ++i) a = fmaf(W3[j * 36 + i], h2[i], a);
        h3[j] = fmaxf(a, 0.0f);
    }
    float x = b4[0];
#pragma unroll
    for (int i = 0; i < 36; ++i) x = fmaf(W4[i], h3[i], x);

    int row = tind[k];
    int col = tind[K + k];
    int r = atomicAdd(&rowcnt[row], 1);
    if (r < cap) {
        u64 pack = ((u64)(unsigned)col << 52) |
                   ((u64)__float_as_uint(x) << 20) |
                   (u64)(unsigned)k;
        rowslot[(size_t)r * n3d + row] = pack;   // slot-major
    }
}

// ---------------------------------------------------------------------------
// Kernel 2: per-row winner resolution + max reduce.
// One thread per row i. Slot-major layout: pass `a` reads rowslot[a*n3d+i],
// fully coalesced across the wave; the O(c^2) duplicate check re-reads the
// same lines from L1. Candidate a survives iff no candidate with the same
// idx1 has a strictly larger k (== last scatter update wins per slot).
// Order-independent -> safe under nondeterministic atomicAdd ordering.
// ---------------------------------------------------------------------------
__global__ __launch_bounds__(256) void row_reduce(
    const int* __restrict__ rowcnt,
    const u64* __restrict__ rowslot,
    float* __restrict__ out,
    int n3d, int cap)
{
    int i = blockIdx.x * 256 + threadIdx.x;
    if (i >= n3d) return;
    int c = rowcnt[i];
    if (c > cap) c = cap;
    float best = FILLV;
    for (int a = 0; a < c; ++a) {
        u64 pa = rowslot[(size_t)a * n3d + i];
        unsigned ja = (unsigned)(pa >> 52);
        unsigned ka = (unsigned)pa & 0xFFFFFu;
        bool win = true;
        for (int b = 0; b < c; ++b) {
            u64 pb = rowslot[(size_t)b * n3d + i];
            if ((unsigned)(pb >> 52) == ja && ((unsigned)pb & 0xFFFFFu) > ka) {
                win = false;
            }
        }
        if (win) best = fmaxf(best, __uint_as_float((unsigned)(pa >> 20)));
    }
    out[i] = best;
}

extern "C" void kernel_launch(void* const* d_in, const int* in_sizes, int n_in,
                              void* d_out, int out_size, void* d_ws, size_t ws_size,
                              hipStream_t stream) {
    const float* input_1 = (const float*)d_in[0];
    // d_in[1] = T_out (never materialized)
    const int*   tind    = (const int*)d_in[2];
    const float* W1 = (const float*)d_in[3];
    const float* b1 = (const float*)d_in[4];
    const float* W2 = (const float*)d_in[5];
    const float* b2 = (const float*)d_in[6];
    const float* W3 = (const float*)d_in[7];
    const float* b3 = (const float*)d_in[8];
    const float* W4 = (const float*)d_in[9];
    const float* b4 = (const float*)d_in[10];
    float* out = (float*)d_out;

    const int K   = in_sizes[0] / 3;   // 800000
    const int n3d = out_size;          // 100000

    // Workspace layout: rowcnt [n3d] ints, then rowslot [cap][n3d] u64.
    size_t cnt_bytes = (size_t)n3d * sizeof(int);
    cnt_bytes = (cnt_bytes + 255) & ~(size_t)255;
    int cap = SLOT_CAP;
    size_t avail = (ws_size > cnt_bytes) ? (ws_size - cnt_bytes) : 0;
    int max_cap = (int)(avail / ((size_t)n3d * sizeof(u64)));
    if (max_cap < cap) cap = max_cap;  // degrade gracefully if ws is tiny

    int* rowcnt = (int*)d_ws;
    u64* rowslot = (u64*)((char*)d_ws + cnt_bytes);

    hipMemsetAsync(rowcnt, 0, (size_t)n3d * sizeof(int), stream);

    int blocks_k = (K + 255) / 256;
    mlp_scatter<<<blocks_k, 256, 0, stream>>>(
        input_1, tind, W1, b1, W2, b2, W3, b3, W4, b4,
        rowcnt, rowslot, K, n3d, cap);

    int blocks_r = (n3d + 255) / 256;
    row_reduce<<<blocks_r, 256, 0, stream>>>(rowcnt, rowslot, out, n3d, cap);
}